// Round 1
// baseline (1128.718 us; speedup 1.0000x reference)
//
#include <hip/hip_runtime.h>
#include <hip/hip_bf16.h>

#define E 128
#define F 128
#define O 64
#define K 8
#define BATCH 2048
#define NIT 32

// ---------------------------------------------------------------------------
// Kernel A: M[k][x][o] = 0.5 * sum_y bilinear[k,x,y] * Q[k,o,y]
// (0.5 = alpha-1 folded in, so the fused GEMM directly produces Xs)
// ---------------------------------------------------------------------------
__global__ __launch_bounds__(256) void precompute_M(const float* __restrict__ Q,
                                                    const float* __restrict__ bil,
                                                    float* __restrict__ M) {
    int idx = blockIdx.x * 256 + threadIdx.x;   // [0, K*E*O)
    int o = idx & 63;
    int x = (idx >> 6) & 127;
    int k = idx >> 13;
    const float4* br = (const float4*)(bil + (size_t)(k * E + x) * E);
    const float4* qr = (const float4*)(Q + (size_t)(k * O + o) * E);
    float acc = 0.f;
#pragma unroll 8
    for (int y = 0; y < E / 4; ++y) {
        float4 bv = br[y], qv = qr[y];
        acc = fmaf(bv.x, qv.x, acc);
        acc = fmaf(bv.y, qv.y, acc);
        acc = fmaf(bv.z, qv.z, acc);
        acc = fmaf(bv.w, qv.w, acc);
    }
    M[idx] = 0.5f * acc;   // M layout: ((k*E + x)*O + o) == idx
}

// ---------------------------------------------------------------------------
// Kernel B: fused  Xs = x_b * M_k  ->  entmax-bisect over f  ->  * values
// Block = 256 threads = 4 waves, handles one (b, k).
// Wave w, lane l: o = w*16 + (l>>2); quad-lane q = l&3 owns f in {16i+4q+t}.
// xT in LDS, transposed [x][f], f-index XOR-swizzled by (x & 28).
// ---------------------------------------------------------------------------
__global__ __launch_bounds__(256, 2) void fused_entmax(const float* __restrict__ xg,
                                                       const float* __restrict__ M,
                                                       const float* __restrict__ values,
                                                       float* __restrict__ out) {
    __shared__ float xT[E * F];   // 64 KB

    int bid = blockIdx.x;
    // XCD swizzle: all 8 heads of one b land on the same XCD, adjacent in time
    int c = bid & 7;
    int j = bid >> 3;
    int k = j & 7;
    int b = ((j >> 3) << 3) | c;

    const float* xb = xg + (size_t)b * (F * E);

    // --- stage x_b transposed into LDS (coalesced float4 global reads) ---
    for (int it = threadIdx.x; it < F * (E / 4); it += 256) {
        int f  = it >> 5;          // 0..127
        int xq = (it & 31) << 2;   // 0,4,...,124
        float4 v = *(const float4*)(xb + f * E + xq);
        xT[(xq + 0) * F + (f ^ ((xq + 0) & 28))] = v.x;
        xT[(xq + 1) * F + (f ^ ((xq + 1) & 28))] = v.y;
        xT[(xq + 2) * F + (f ^ ((xq + 2) & 28))] = v.z;
        xT[(xq + 3) * F + (f ^ ((xq + 3) & 28))] = v.w;
    }
    __syncthreads();

    int w  = threadIdx.x >> 6;
    int l  = threadIdx.x & 63;
    int ol = l >> 2, q = l & 3;
    int o  = w * 16 + ol;
    int fq = q << 2;                       // 0,4,8,12
    const float* Mk = M + (size_t)k * (E * O);

    // --- GEMM: acc[i][t] = Xs[b,k,o, f=16i+fq+t] ---
    float acc[8][4];
#pragma unroll
    for (int i = 0; i < 8; ++i)
#pragma unroll
        for (int t = 0; t < 4; ++t) acc[i][t] = 0.f;

    for (int x0 = 0; x0 < E; x0 += 8) {
        float mbuf[8];
#pragma unroll
        for (int u = 0; u < 8; ++u) mbuf[u] = Mk[(x0 + u) * O + o];
#pragma unroll
        for (int u = 0; u < 8; ++u) {
            int xx  = x0 + u;
            int xsw = xx & 28;
            const float* xrow = &xT[xx * F];
            float m = mbuf[u];
#pragma unroll
            for (int i = 0; i < 8; ++i) {
                float4 v = *(const float4*)(xrow + ((16 * i + fq) ^ xsw));
                acc[i][0] = fmaf(m, v.x, acc[i][0]);
                acc[i][1] = fmaf(m, v.y, acc[i][1]);
                acc[i][2] = fmaf(m, v.z, acc[i][2]);
                acc[i][3] = fmaf(m, v.w, acc[i][3]);
            }
        }
    }

    // --- entmax bisection over the row (128 elems across the 4-lane quad) ---
    float mx = -1e30f;
#pragma unroll
    for (int i = 0; i < 8; ++i)
#pragma unroll
        for (int t = 0; t < 4; ++t) mx = fmaxf(mx, acc[i][t]);
    mx = fmaxf(mx, __shfl_xor(mx, 1));
    mx = fmaxf(mx, __shfl_xor(mx, 2));

    float tau_lo = mx - 1.0f;
    float tau_hi = mx - 0.08838834764831845f;   // (1/128)^(alpha-1)
    float dm = tau_hi - tau_lo;

    float f_lo = 0.f;
#pragma unroll
    for (int i = 0; i < 8; ++i)
#pragma unroll
        for (int t = 0; t < 4; ++t) {
            float d = fmaxf(acc[i][t] - tau_lo, 0.f);
            f_lo = fmaf(d, d, f_lo);
        }
    f_lo += __shfl_xor(f_lo, 1);
    f_lo += __shfl_xor(f_lo, 2);
    f_lo -= 1.0f;

    float tau_m = tau_hi;
    for (int it = 0; it < NIT; ++it) {
        dm *= 0.5f;
        tau_m = tau_lo + dm;
        float fm = 0.f;
#pragma unroll
        for (int i = 0; i < 8; ++i)
#pragma unroll
            for (int t = 0; t < 4; ++t) {
                float d = fmaxf(acc[i][t] - tau_m, 0.f);
                fm = fmaf(d, d, fm);
            }
        fm += __shfl_xor(fm, 1);
        fm += __shfl_xor(fm, 2);
        fm -= 1.0f;
        if (fm * f_lo >= 0.f) tau_lo = tau_m;
    }

    // --- normalize + scale by values, write out ---
    float s = 0.f;
#pragma unroll
    for (int i = 0; i < 8; ++i)
#pragma unroll
        for (int t = 0; t < 4; ++t) {
            float d = fmaxf(acc[i][t] - tau_m, 0.f);
            s = fmaf(d, d, s);
        }
    s += __shfl_xor(s, 1);
    s += __shfl_xor(s, 2);
    float inv = 1.0f / s;

    const float* vrow = values + (size_t)(k * O + o) * F;
    float* orow = out + (((size_t)b * K + k) * O + o) * (size_t)F;
#pragma unroll
    for (int i = 0; i < 8; ++i) {
        int fb = 16 * i + fq;
        float4 vv = *(const float4*)(vrow + fb);
        float d0 = fmaxf(acc[i][0] - tau_m, 0.f);
        float d1 = fmaxf(acc[i][1] - tau_m, 0.f);
        float d2 = fmaxf(acc[i][2] - tau_m, 0.f);
        float d3 = fmaxf(acc[i][3] - tau_m, 0.f);
        float4 ov;
        ov.x = d0 * d0 * inv * vv.x;
        ov.y = d1 * d1 * inv * vv.y;
        ov.z = d2 * d2 * inv * vv.z;
        ov.w = d3 * d3 * inv * vv.w;
        *(float4*)(orow + fb) = ov;
    }
}

extern "C" void kernel_launch(void* const* d_in, const int* in_sizes, int n_in,
                              void* d_out, int out_size, void* d_ws, size_t ws_size,
                              hipStream_t stream) {
    const float* x      = (const float*)d_in[0];   // [B, F, E]
    const float* Q      = (const float*)d_in[1];   // [K, O, E]
    const float* bil    = (const float*)d_in[2];   // [K, E, E]
    const float* values = (const float*)d_in[3];   // [K, O, F]
    float* out = (float*)d_out;                    // [B, K, O, F]
    float* M   = (float*)d_ws;                     // [K, E, O] = 256 KB scratch

    precompute_M<<<(K * E * O) / 256, 256, 0, stream>>>(Q, bil, M);
    fused_entmax<<<BATCH * K, 256, 0, stream>>>(x, M, values, out);
}

// Round 2
// 811.272 us; speedup vs baseline: 1.3913x; 1.3913x over previous
//
#include <hip/hip_runtime.h>
#include <hip/hip_bf16.h>

#define E 128
#define F 128
#define O 64
#define K 8
#define BATCH 2048
#define NIT 28

// ---------------------------------------------------------------------------
// Kernel A: M[k][x][o] = 0.5 * sum_y bilinear[k,x,y] * Q[k,o,y]
// (0.5 = alpha-1 folded in, so the fused GEMM directly produces Xs)
// ---------------------------------------------------------------------------
__global__ __launch_bounds__(256) void precompute_M(const float* __restrict__ Q,
                                                    const float* __restrict__ bil,
                                                    float* __restrict__ M) {
    int idx = blockIdx.x * 256 + threadIdx.x;   // [0, K*E*O)
    int o = idx & 63;
    int x = (idx >> 6) & 127;
    int k = idx >> 13;
    const float4* br = (const float4*)(bil + (size_t)(k * E + x) * E);
    const float4* qr = (const float4*)(Q + (size_t)(k * O + o) * E);
    float acc = 0.f;
#pragma unroll 8
    for (int y = 0; y < E / 4; ++y) {
        float4 bv = br[y], qv = qr[y];
        acc = fmaf(bv.x, qv.x, acc);
        acc = fmaf(bv.y, qv.y, acc);
        acc = fmaf(bv.z, qv.z, acc);
        acc = fmaf(bv.w, qv.w, acc);
    }
    M[idx] = 0.5f * acc;   // layout ((k*E + x)*O + o)
}

// swizzle: injective per x-row, keeps float4 alignment (touches bits 2..4 only),
// spreads the 16 wave-unique read addresses across all 32 banks (2-way = free),
// and breaks the 32-way transpose-write conflict.
__device__ __forceinline__ int swzf(int x, int f) {
    return f ^ (x & 28) ^ ((f >> 3) & 12);
}

__device__ __forceinline__ float rsum16(float v) {
    v += __shfl_xor(v, 1);
    v += __shfl_xor(v, 2);
    v += __shfl_xor(v, 4);
    v += __shfl_xor(v, 8);
    return v;
}

__device__ __forceinline__ float rmax16(float v) {
    v = fmaxf(v, __shfl_xor(v, 1));
    v = fmaxf(v, __shfl_xor(v, 2));
    v = fmaxf(v, __shfl_xor(v, 4));
    v = fmaxf(v, __shfl_xor(v, 8));
    return v;
}

// ---------------------------------------------------------------------------
// Kernel B: fused  Xs = x_b * M_k  ->  entmax-bisect over f  ->  * values
// Block = 256 threads = 4 waves, one (b,k). Lane l: fl=l&15 owns f in
// [fl*8, fl*8+8); og=l>>4 with wave w owns o in [w*16+og*4, +4).
// x staged transposed in two 32KB halves (4 blocks/CU). LDS reads are
// 4-way lane-broadcast (quad-of-lanes share fl) -> 256B unique per b128.
// ---------------------------------------------------------------------------
__global__ __launch_bounds__(256, 4) void fused_entmax(const float* __restrict__ xg,
                                                       const float* __restrict__ M,
                                                       const float* __restrict__ values,
                                                       float* __restrict__ out) {
    __shared__ float4 xT4[64 * 32];          // 32 KB: xT[x_local][f] swizzled
    float* xT = (float*)xT4;

    int bid = blockIdx.x;
    // XCD swizzle: the 8 heads of one b are time-adjacent on one XCD (x L2 reuse)
    int c = bid & 7;
    int jj = bid >> 3;
    int k = jj & 7;
    int b = ((jj >> 3) << 3) | c;

    const float* xb = xg + (size_t)b * (F * E);
    const float* Mk = M + (size_t)k * (E * O);

    int tid = threadIdx.x;
    int w   = tid >> 6;
    int l   = tid & 63;
    int fl  = l & 15;
    int og  = l >> 4;
    int obase = w * 16 + og * 4;
    int f0  = fl * 8;

    float acc[4][8];
#pragma unroll
    for (int oj = 0; oj < 4; ++oj)
#pragma unroll
        for (int i = 0; i < 8; ++i) acc[oj][i] = 0.f;

    for (int h = 0; h < 2; ++h) {
        if (h) __syncthreads();              // WAR on LDS before re-staging
        // --- stage half h: x columns [h*64, h*64+64), transposed+swizzled ---
#pragma unroll
        for (int p = 0; p < 8; ++p) {
            int it = tid + p * 256;
            int f  = it >> 4;                // 0..127
            int xq = (it & 15) << 2;         // 0..60 (local x)
            float4 v = *(const float4*)(xb + f * E + h * 64 + xq);
            xT[(xq + 0) * 128 + swzf(xq + 0, f)] = v.x;
            xT[(xq + 1) * 128 + swzf(xq + 1, f)] = v.y;
            xT[(xq + 2) * 128 + swzf(xq + 2, f)] = v.z;
            xT[(xq + 3) * 128 + swzf(xq + 3, f)] = v.w;
        }
        __syncthreads();

        // --- GEMM over this half's x ---
        for (int x0 = 0; x0 < 64; x0 += 4) {
            int xgl = h * 64 + x0;
            float4 mv0 = *(const float4*)(Mk + (xgl + 0) * O + obase);
            float4 mv1 = *(const float4*)(Mk + (xgl + 1) * O + obase);
            float4 mv2 = *(const float4*)(Mk + (xgl + 2) * O + obase);
            float4 mv3 = *(const float4*)(Mk + (xgl + 3) * O + obase);
#pragma unroll
            for (int u = 0; u < 4; ++u) {
                int xx = x0 + u;
                float4 mu = (u == 0) ? mv0 : (u == 1) ? mv1 : (u == 2) ? mv2 : mv3;
                float4 a0 = xT4[(xx * 128 + swzf(xx, f0)) >> 2];
                float4 a1 = xT4[(xx * 128 + swzf(xx, f0 + 4)) >> 2];
                float xv[8] = {a0.x, a0.y, a0.z, a0.w, a1.x, a1.y, a1.z, a1.w};
                float mo[4] = {mu.x, mu.y, mu.z, mu.w};
#pragma unroll
                for (int oj = 0; oj < 4; ++oj)
#pragma unroll
                    for (int i = 0; i < 8; ++i)
                        acc[oj][i] = fmaf(mo[oj], xv[i], acc[oj][i]);
            }
        }
    }

    // --- entmax bisection: 4 independent rows/thread, each spread over 16 lanes ---
    float tlo[4], flo[4], tmv[4], fmv[4];
#pragma unroll
    for (int oj = 0; oj < 4; ++oj) {
        float mx = acc[oj][0];
#pragma unroll
        for (int i = 1; i < 8; ++i) mx = fmaxf(mx, acc[oj][i]);
        mx = rmax16(mx);
        float t = mx - 1.0f;
        float s = 0.f;
#pragma unroll
        for (int i = 0; i < 8; ++i) {
            float d = fmaxf(acc[oj][i] - t, 0.f);
            s = fmaf(d, d, s);
        }
        s = rsum16(s) - 1.0f;
        tlo[oj] = t;
        flo[oj] = s;
        tmv[oj] = mx - 0.08838834764831845f;   // tau_hi = mx - (1/128)^(alpha-1)
        fmv[oj] = 0.f;
    }

    float dm = 0.91161165235168155f;           // tau_hi - tau_lo (data-independent)
    for (int it = 0; it < NIT; ++it) {
        dm *= 0.5f;
#pragma unroll
        for (int oj = 0; oj < 4; ++oj) {
            float tm = tlo[oj] + dm;
            float s = 0.f;
#pragma unroll
            for (int i = 0; i < 8; ++i) {
                float d = fmaxf(acc[oj][i] - tm, 0.f);
                s = fmaf(d, d, s);
            }
            s = rsum16(s) - 1.0f;
            if (s * flo[oj] >= 0.f) tlo[oj] = tm;
            tmv[oj] = tm;
            fmv[oj] = s;      // f(tau_m) of the LAST iteration -> normalizer
        }
    }

    // --- normalize + scale by values, write out ---
#pragma unroll
    for (int oj = 0; oj < 4; ++oj) {
        int o = obase + oj;
        float tm  = tmv[oj];
        float inv = 1.0f / (fmv[oj] + 1.0f);
        const float* vr = values + (size_t)(k * O + o) * F + f0;
        float* orow = out + (((size_t)b * K + k) * O + o) * (size_t)F + f0;
        float4 v0 = *(const float4*)(vr);
        float4 v1 = *(const float4*)(vr + 4);
        float d[8];
#pragma unroll
        for (int i = 0; i < 8; ++i) d[i] = fmaxf(acc[oj][i] - tm, 0.f);
        float4 o0, o1;
        o0.x = d[0] * d[0] * inv * v0.x;
        o0.y = d[1] * d[1] * inv * v0.y;
        o0.z = d[2] * d[2] * inv * v0.z;
        o0.w = d[3] * d[3] * inv * v0.w;
        o1.x = d[4] * d[4] * inv * v1.x;
        o1.y = d[5] * d[5] * inv * v1.y;
        o1.z = d[6] * d[6] * inv * v1.z;
        o1.w = d[7] * d[7] * inv * v1.w;
        *(float4*)(orow)     = o0;
        *(float4*)(orow + 4) = o1;
    }
}

extern "C" void kernel_launch(void* const* d_in, const int* in_sizes, int n_in,
                              void* d_out, int out_size, void* d_ws, size_t ws_size,
                              hipStream_t stream) {
    const float* x      = (const float*)d_in[0];   // [B, F, E]
    const float* Q      = (const float*)d_in[1];   // [K, O, E]
    const float* bil    = (const float*)d_in[2];   // [K, E, E]
    const float* values = (const float*)d_in[3];   // [K, O, F]
    float* out = (float*)d_out;                    // [B, K, O, F]
    float* M   = (float*)d_ws;                     // [K, E, O] scratch (256 KB)

    precompute_M<<<(K * E * O) / 256, 256, 0, stream>>>(Q, bil, M);
    fused_entmax<<<BATCH * K, 256, 0, stream>>>(x, M, values, out);
}

// Round 3
// 638.272 us; speedup vs baseline: 1.7684x; 1.2710x over previous
//
#include <hip/hip_runtime.h>
#include <hip/hip_bf16.h>

#define E 128
#define F 128
#define O 64
#define K 8
#define BATCH 2048
#define NEWTON_IT 11

// ---------------------------------------------------------------------------
// Kernel A: M[k][x][o] = 0.5 * sum_y bilinear[k,x,y] * Q[k,o,y]
// (0.5 = alpha-1 folded in, so the fused GEMM directly produces Xs)
// ---------------------------------------------------------------------------
__global__ __launch_bounds__(256) void precompute_M(const float* __restrict__ Q,
                                                    const float* __restrict__ bil,
                                                    float* __restrict__ M) {
    int idx = blockIdx.x * 256 + threadIdx.x;   // [0, K*E*O)
    int o = idx & 63;
    int x = (idx >> 6) & 127;
    int k = idx >> 13;
    const float4* br = (const float4*)(bil + (size_t)(k * E + x) * E);
    const float4* qr = (const float4*)(Q + (size_t)(k * O + o) * E);
    float acc = 0.f;
#pragma unroll 8
    for (int y = 0; y < E / 4; ++y) {
        float4 bv = br[y], qv = qr[y];
        acc = fmaf(bv.x, qv.x, acc);
        acc = fmaf(bv.y, qv.y, acc);
        acc = fmaf(bv.z, qv.z, acc);
        acc = fmaf(bv.w, qv.w, acc);
    }
    M[idx] = 0.5f * acc;   // layout ((k*E + x)*O + o)
}

// swizzle for the x-staging tile: injective per x-row, float4-aligned,
// spreads wave read addresses 2-way across banks, breaks transpose-write 32-way.
__device__ __forceinline__ int swzf(int x, int f) {
    return f ^ (x & 28) ^ ((f >> 3) & 12);
}

// ---------------------------------------------------------------------------
// Kernel B: fused  Xs = x_b * M_k  ->  entmax (Newton)  ->  * values
// Block = 256 threads = 4 waves, one (b,k).
// GEMM phase: lane l: fl=l&15 owns f in [fl*8,+8); og=l>>4, wave w owns
//   o in [w*16+og*4,+4). x staged transposed+swizzled in two 32KB halves.
// Entmax phase: acc transposed via LDS (stride-132 rows). Thread t owns row
//   o=t>>2, quad-lane q=t&3 owns f in {q*4+16j}. All reductions are
//   __shfl_xor 1/2 (DPP quad ops, VALU pipe) — no ds_swizzle in hot loop.
// ---------------------------------------------------------------------------
__global__ __launch_bounds__(256, 4) void fused_entmax(const float* __restrict__ xg,
                                                       const float* __restrict__ M,
                                                       const float* __restrict__ values,
                                                       float* __restrict__ out) {
    __shared__ float4 ldsv[2112];            // 33792 B = 64 x 132 floats
    float* lds = (float*)ldsv;

    int bid = blockIdx.x;
    // XCD swizzle: the 8 heads of one b are time-adjacent on one XCD (x L2 reuse)
    int c = bid & 7;
    int jj = bid >> 3;
    int k = jj & 7;
    int b = ((jj >> 3) << 3) | c;

    const float* xb = xg + (size_t)b * (F * E);
    const float* Mk = M + (size_t)k * (E * O);

    int tid = threadIdx.x;
    int w   = tid >> 6;
    int l   = tid & 63;
    int fl  = l & 15;
    int og  = l >> 4;
    int obase = w * 16 + og * 4;
    int f0  = fl * 8;

    float acc[4][8];
#pragma unroll
    for (int oj = 0; oj < 4; ++oj)
#pragma unroll
        for (int i = 0; i < 8; ++i) acc[oj][i] = 0.f;

    for (int h = 0; h < 2; ++h) {
        if (h) __syncthreads();              // WAR on LDS before re-staging
#pragma unroll
        for (int p = 0; p < 8; ++p) {
            int it = tid + p * 256;
            int f  = it >> 4;                // 0..127
            int xq = (it & 15) << 2;         // 0..60 (local x)
            float4 v = *(const float4*)(xb + f * E + h * 64 + xq);
            lds[(xq + 0) * 128 + swzf(xq + 0, f)] = v.x;
            lds[(xq + 1) * 128 + swzf(xq + 1, f)] = v.y;
            lds[(xq + 2) * 128 + swzf(xq + 2, f)] = v.z;
            lds[(xq + 3) * 128 + swzf(xq + 3, f)] = v.w;
        }
        __syncthreads();

        for (int x0 = 0; x0 < 64; x0 += 4) {
            int xgl = h * 64 + x0;
            float4 mv0 = *(const float4*)(Mk + (xgl + 0) * O + obase);
            float4 mv1 = *(const float4*)(Mk + (xgl + 1) * O + obase);
            float4 mv2 = *(const float4*)(Mk + (xgl + 2) * O + obase);
            float4 mv3 = *(const float4*)(Mk + (xgl + 3) * O + obase);
#pragma unroll
            for (int u = 0; u < 4; ++u) {
                int xx = x0 + u;
                float4 mu = (u == 0) ? mv0 : (u == 1) ? mv1 : (u == 2) ? mv2 : mv3;
                float4 a0 = ldsv[(xx * 128 + swzf(xx, f0)) >> 2];
                float4 a1 = ldsv[(xx * 128 + swzf(xx, f0 + 4)) >> 2];
                float xv[8] = {a0.x, a0.y, a0.z, a0.w, a1.x, a1.y, a1.z, a1.w};
                float mo[4] = {mu.x, mu.y, mu.z, mu.w};
#pragma unroll
                for (int oj = 0; oj < 4; ++oj)
#pragma unroll
                    for (int i = 0; i < 8; ++i)
                        acc[oj][i] = fmaf(mo[oj], xv[i], acc[oj][i]);
            }
        }
    }

    // --- transpose acc via LDS: [o][f] with stride 132 (pad kills 4-way) ---
    __syncthreads();
#pragma unroll
    for (int oj = 0; oj < 4; ++oj) {
        int o = obase + oj;
        float4 w0 = {acc[oj][0], acc[oj][1], acc[oj][2], acc[oj][3]};
        float4 w1 = {acc[oj][4], acc[oj][5], acc[oj][6], acc[oj][7]};
        *(float4*)&lds[o * 132 + f0]     = w0;
        *(float4*)&lds[o * 132 + f0 + 4] = w1;
    }
    __syncthreads();

    int orow = tid >> 2;        // 0..63
    int q    = tid & 3;         // f chunks q*4 + 16j
    float z[32];
#pragma unroll
    for (int j = 0; j < 8; ++j) {
        float4 v = *(const float4*)&lds[orow * 132 + q * 4 + 16 * j];
        z[4 * j + 0] = v.x;
        z[4 * j + 1] = v.y;
        z[4 * j + 2] = v.z;
        z[4 * j + 3] = v.w;
    }

    // --- row max (quad reduce: xor1/xor2 = DPP) ---
    float m0 = z[0], m1 = z[1], m2 = z[2], m3 = z[3];
#pragma unroll
    for (int i = 4; i < 32; i += 4) {
        m0 = fmaxf(m0, z[i]);
        m1 = fmaxf(m1, z[i + 1]);
        m2 = fmaxf(m2, z[i + 2]);
        m3 = fmaxf(m3, z[i + 3]);
    }
    float mx = fmaxf(fmaxf(m0, m1), fmaxf(m2, m3));
    mx = fmaxf(mx, __shfl_xor(mx, 1));
    mx = fmaxf(mx, __shfl_xor(mx, 2));

    // --- Newton on f(t) = sum relu(z-t)^2 - 1, from t0 = mx-1 (f>=0) ---
    float t = mx - 1.0f;
#pragma unroll
    for (int it = 0; it < NEWTON_IT; ++it) {
        float s0 = 0.f, s1 = 0.f, s2 = 0.f, s3 = 0.f;
        float a0 = 0.f, a1 = 0.f;
#pragma unroll
        for (int i = 0; i < 32; i += 4) {
            float d0 = fmaxf(z[i] - t, 0.f);
            float d1 = fmaxf(z[i + 1] - t, 0.f);
            float d2 = fmaxf(z[i + 2] - t, 0.f);
            float d3 = fmaxf(z[i + 3] - t, 0.f);
            s0 = fmaf(d0, d0, s0);
            s1 = fmaf(d1, d1, s1);
            s2 = fmaf(d2, d2, s2);
            s3 = fmaf(d3, d3, s3);
            a0 += d0 + d1;
            a1 += d2 + d3;
        }
        float s  = (s0 + s1) + (s2 + s3);
        float sl = a0 + a1;
        s  += __shfl_xor(s, 1);
        s  += __shfl_xor(s, 2);
        sl += __shfl_xor(sl, 1);
        sl += __shfl_xor(sl, 2);
        t += (s - 1.0f) / (sl + sl);   // convex, from below: never overshoots
    }

    // --- final eval at converged t -> p, normalizer ---
    float d[32];
    float s0 = 0.f, s1 = 0.f, s2 = 0.f, s3 = 0.f;
#pragma unroll
    for (int i = 0; i < 32; i += 4) {
        d[i]     = fmaxf(z[i] - t, 0.f);
        d[i + 1] = fmaxf(z[i + 1] - t, 0.f);
        d[i + 2] = fmaxf(z[i + 2] - t, 0.f);
        d[i + 3] = fmaxf(z[i + 3] - t, 0.f);
        s0 = fmaf(d[i], d[i], s0);
        s1 = fmaf(d[i + 1], d[i + 1], s1);
        s2 = fmaf(d[i + 2], d[i + 2], s2);
        s3 = fmaf(d[i + 3], d[i + 3], s3);
    }
    float s = (s0 + s1) + (s2 + s3);
    s += __shfl_xor(s, 1);
    s += __shfl_xor(s, 2);
    float inv = 1.0f / s;

    // --- scale by values, write out (q*4+16j chunks -> 64B-coalesced) ---
    const float* vr = values + (size_t)(k * O + orow) * F;
    float* orow_p = out + (((size_t)b * K + k) * O + orow) * (size_t)F;
#pragma unroll
    for (int j = 0; j < 8; ++j) {
        int fb = q * 4 + 16 * j;
        float4 vv = *(const float4*)(vr + fb);
        float4 ov;
        ov.x = d[4 * j + 0] * d[4 * j + 0] * inv * vv.x;
        ov.y = d[4 * j + 1] * d[4 * j + 1] * inv * vv.y;
        ov.z = d[4 * j + 2] * d[4 * j + 2] * inv * vv.z;
        ov.w = d[4 * j + 3] * d[4 * j + 3] * inv * vv.w;
        *(float4*)(orow_p + fb) = ov;
    }
}

extern "C" void kernel_launch(void* const* d_in, const int* in_sizes, int n_in,
                              void* d_out, int out_size, void* d_ws, size_t ws_size,
                              hipStream_t stream) {
    const float* x      = (const float*)d_in[0];   // [B, F, E]
    const float* Q      = (const float*)d_in[1];   // [K, O, E]
    const float* bil    = (const float*)d_in[2];   // [K, E, E]
    const float* values = (const float*)d_in[3];   // [K, O, F]
    float* out = (float*)d_out;                    // [B, K, O, F]
    float* M   = (float*)d_ws;                     // [K, E, O] scratch (256 KB)

    precompute_M<<<(K * E * O) / 256, 256, 0, stream>>>(Q, bil, M);
    fused_entmax<<<BATCH * K, 256, 0, stream>>>(x, M, values, out);
}

// Round 4
// 448.146 us; speedup vs baseline: 2.5186x; 1.4243x over previous
//
#include <hip/hip_runtime.h>
#include <hip/hip_bf16.h>

#define E 128
#define F 128
#define O 64
#define K 8
#define BATCH 2048
#define NEWTON_IT 9

typedef __attribute__((ext_vector_type(8))) short bf8;     // 8 bf16 (4 VGPR)
typedef __attribute__((ext_vector_type(16))) float f16x;   // MFMA 32x32 accumulator

// ---------------------------------------------------------------------------
// Kernel A: M^T[k][o][x] = 0.5 * sum_y bil[k,x,y] * Q[k,o,y], stored as two
// truncated-bf16 planes (hi, lo) so kernel B's MFMA A-fragments load directly.
// ---------------------------------------------------------------------------
__global__ __launch_bounds__(256) void precompute_M(const float* __restrict__ Q,
                                                    const float* __restrict__ bil,
                                                    unsigned short* __restrict__ Mhi,
                                                    unsigned short* __restrict__ Mlo) {
    int idx = blockIdx.x * 256 + threadIdx.x;   // ((k*O + o)*E + x)
    int x  = idx & 127;
    int o  = (idx >> 7) & 63;
    int kk = idx >> 13;
    const float4* br = (const float4*)(bil + (size_t)(kk * E + x) * E);
    const float4* qr = (const float4*)(Q + (size_t)(kk * O + o) * E);
    float acc = 0.f;
#pragma unroll 8
    for (int y = 0; y < E / 4; ++y) {
        float4 bv = br[y], qv = qr[y];
        acc = fmaf(bv.x, qv.x, acc);
        acc = fmaf(bv.y, qv.y, acc);
        acc = fmaf(bv.z, qv.z, acc);
        acc = fmaf(bv.w, qv.w, acc);
    }
    float m = 0.5f * acc;
    unsigned um = __float_as_uint(m);
    float hi = __uint_as_float(um & 0xFFFF0000u);
    float lo = m - hi;
    Mhi[idx] = (unsigned short)(um >> 16);
    Mlo[idx] = (unsigned short)(__float_as_uint(lo) >> 16);
}

// split a,b into truncated-bf16 hi words + lo words, packed pairwise
#define SPLIT_PK(a, b, hw, lw)                                              \
    {                                                                       \
        unsigned ua = __float_as_uint(a), ub = __float_as_uint(b);          \
        float la = (a) - __uint_as_float(ua & 0xFFFF0000u);                 \
        float lb = (b) - __uint_as_float(ub & 0xFFFF0000u);                 \
        hw = (ua >> 16) | (ub & 0xFFFF0000u);                               \
        lw = (__float_as_uint(la) >> 16) | (__float_as_uint(lb) & 0xFFFF0000u); \
    }

// ---------------------------------------------------------------------------
// Kernel B: MFMA GEMM (2-way bf16 split, 3 products) -> LDS transpose ->
// Newton entmax -> * values.
// 4 waves per block, one (b,k). Wave w: f in [32w, 32w+32) (B in regs),
// o-tiles {0,1} (A streamed from L2). C: col = l&31 = f_local,
// row = (r&3)+8*(r>>2)+4*(l>>5) = o_local.
// ---------------------------------------------------------------------------
__global__ __launch_bounds__(256, 3) void fused_entmax(
        const float* __restrict__ xg,
        const unsigned short* __restrict__ Mhi,
        const unsigned short* __restrict__ Mlo,
        const float* __restrict__ values,
        float* __restrict__ out) {
    __shared__ float lds[O * 132];           // 33792 B

    int bid = blockIdx.x;
    // XCD swizzle: 8 heads of one b time-adjacent on one XCD (x L2 reuse)
    int c = bid & 7, jj = bid >> 3;
    int kh = jj & 7;
    int b  = ((jj >> 3) << 3) | c;

    const float* xb = xg + (size_t)b * (F * E);
    const unsigned short* mh = Mhi + (size_t)kh * (O * E);
    const unsigned short* ml = Mlo + (size_t)kh * (O * E);

    int tid  = threadIdx.x;
    int w    = tid >> 6, l = tid & 63;
    int lo31 = l & 31;
    int xh   = (l >> 5) << 3;                // K-chunk: 0 or 8
    int fcol = w * 32 + lo31;

    // ---- B operand: x[f=fcol][x], 8 ksteps x 8 contiguous x, split hi/lo ----
    bf8 Bh[8], Bl[8];
#pragma unroll
    for (int s = 0; s < 8; ++s) {
        const float* p = xb + (size_t)fcol * E + s * 16 + xh;
        float4 v0 = *(const float4*)p;
        float4 v1 = *(const float4*)(p + 4);
        union { bf8 v; unsigned u[4]; } H, L;
        SPLIT_PK(v0.x, v0.y, H.u[0], L.u[0]);
        SPLIT_PK(v0.z, v0.w, H.u[1], L.u[1]);
        SPLIT_PK(v1.x, v1.y, H.u[2], L.u[2]);
        SPLIT_PK(v1.z, v1.w, H.u[3], L.u[3]);
        Bh[s] = H.v;
        Bl[s] = L.v;
    }

    // ---- MFMA K-loop: acc = (Ah+Al)(Bh+Bl) minus Al*Bl ----
    f16x acc0{}, acc1{};
#pragma unroll
    for (int s = 0; s < 8; ++s) {
        int xoff = s * 16 + xh;
        bf8 a0h = *(const bf8*)(mh + (size_t)lo31 * E + xoff);
        bf8 a0l = *(const bf8*)(ml + (size_t)lo31 * E + xoff);
        bf8 a1h = *(const bf8*)(mh + (size_t)(lo31 + 32) * E + xoff);
        bf8 a1l = *(const bf8*)(ml + (size_t)(lo31 + 32) * E + xoff);
        acc0 = __builtin_amdgcn_mfma_f32_32x32x16_bf16(a0l, Bh[s], acc0, 0, 0, 0);
        acc0 = __builtin_amdgcn_mfma_f32_32x32x16_bf16(a0h, Bl[s], acc0, 0, 0, 0);
        acc0 = __builtin_amdgcn_mfma_f32_32x32x16_bf16(a0h, Bh[s], acc0, 0, 0, 0);
        acc1 = __builtin_amdgcn_mfma_f32_32x32x16_bf16(a1l, Bh[s], acc1, 0, 0, 0);
        acc1 = __builtin_amdgcn_mfma_f32_32x32x16_bf16(a1h, Bl[s], acc1, 0, 0, 0);
        acc1 = __builtin_amdgcn_mfma_f32_32x32x16_bf16(a1h, Bh[s], acc1, 0, 0, 0);
    }

    // ---- transpose C into lds[o][f] (stride 132; bank-clean writes) ----
#pragma unroll
    for (int r = 0; r < 16; ++r) {
        int orow = (r & 3) + ((r >> 2) << 3) + ((l >> 5) << 2);
        lds[orow * 132 + fcol]        = acc0[r];
        lds[(orow + 32) * 132 + fcol] = acc1[r];
    }
    __syncthreads();

    // ---- Newton entmax: thread t owns row o=t>>2, quad-lane q=t&3 ----
    int orow = tid >> 2;
    int q    = tid & 3;
    float z[32];
#pragma unroll
    for (int j = 0; j < 8; ++j) {
        float4 v = *(const float4*)&lds[orow * 132 + q * 4 + 16 * j];
        z[4 * j + 0] = v.x;
        z[4 * j + 1] = v.y;
        z[4 * j + 2] = v.z;
        z[4 * j + 3] = v.w;
    }

    float m0 = z[0], m1 = z[1], m2 = z[2], m3 = z[3];
#pragma unroll
    for (int i = 4; i < 32; i += 4) {
        m0 = fmaxf(m0, z[i]);
        m1 = fmaxf(m1, z[i + 1]);
        m2 = fmaxf(m2, z[i + 2]);
        m3 = fmaxf(m3, z[i + 3]);
    }
    float mx = fmaxf(fmaxf(m0, m1), fmaxf(m2, m3));
    mx = fmaxf(mx, __shfl_xor(mx, 1));
    mx = fmaxf(mx, __shfl_xor(mx, 2));

    // Newton on f(t) = sum relu(z-t)^2 - 1 from t0 = mx-1 (f>=0, monotone up)
    float t = mx - 1.0f;
#pragma unroll
    for (int it = 0; it < NEWTON_IT; ++it) {
        float s0 = 0.f, s1 = 0.f, s2 = 0.f, s3 = 0.f;
        float a0 = 0.f, a1 = 0.f;
#pragma unroll
        for (int i = 0; i < 32; i += 4) {
            float d0 = fmaxf(z[i] - t, 0.f);
            float d1 = fmaxf(z[i + 1] - t, 0.f);
            float d2 = fmaxf(z[i + 2] - t, 0.f);
            float d3 = fmaxf(z[i + 3] - t, 0.f);
            s0 = fmaf(d0, d0, s0);
            s1 = fmaf(d1, d1, s1);
            s2 = fmaf(d2, d2, s2);
            s3 = fmaf(d3, d3, s3);
            a0 += d0 + d1;
            a1 += d2 + d3;
        }
        float s  = (s0 + s1) + (s2 + s3);
        float sl = a0 + a1;
        s  += __shfl_xor(s, 1);
        s  += __shfl_xor(s, 2);
        sl += __shfl_xor(sl, 1);
        sl += __shfl_xor(sl, 2);
        t += (s - 1.0f) / (sl + sl);
    }

    float d[32];
    float s0 = 0.f, s1 = 0.f, s2 = 0.f, s3 = 0.f;
#pragma unroll
    for (int i = 0; i < 32; i += 4) {
        d[i]     = fmaxf(z[i] - t, 0.f);
        d[i + 1] = fmaxf(z[i + 1] - t, 0.f);
        d[i + 2] = fmaxf(z[i + 2] - t, 0.f);
        d[i + 3] = fmaxf(z[i + 3] - t, 0.f);
        s0 = fmaf(d[i], d[i], s0);
        s1 = fmaf(d[i + 1], d[i + 1], s1);
        s2 = fmaf(d[i + 2], d[i + 2], s2);
        s3 = fmaf(d[i + 3], d[i + 3], s3);
    }
    float s = (s0 + s1) + (s2 + s3);
    s += __shfl_xor(s, 1);
    s += __shfl_xor(s, 2);
    float inv = 1.0f / s;

    const float* vr = values + (size_t)(kh * O + orow) * F;
    float* orow_p = out + (((size_t)b * K + kh) * O + orow) * (size_t)F;
#pragma unroll
    for (int j = 0; j < 8; ++j) {
        int fb = q * 4 + 16 * j;
        float4 vv = *(const float4*)(vr + fb);
        float4 ov;
        ov.x = d[4 * j + 0] * d[4 * j + 0] * inv * vv.x;
        ov.y = d[4 * j + 1] * d[4 * j + 1] * inv * vv.y;
        ov.z = d[4 * j + 2] * d[4 * j + 2] * inv * vv.z;
        ov.w = d[4 * j + 3] * d[4 * j + 3] * inv * vv.w;
        *(float4*)(orow_p + fb) = ov;
    }
}

extern "C" void kernel_launch(void* const* d_in, const int* in_sizes, int n_in,
                              void* d_out, int out_size, void* d_ws, size_t ws_size,
                              hipStream_t stream) {
    const float* x      = (const float*)d_in[0];   // [B, F, E]
    const float* Q      = (const float*)d_in[1];   // [K, O, E]
    const float* bil    = (const float*)d_in[2];   // [K, E, E]
    const float* values = (const float*)d_in[3];   // [K, O, F]
    float* out = (float*)d_out;                    // [B, K, O, F]

    unsigned short* Mhi = (unsigned short*)d_ws;           // [K][O][E] bf16 hi
    unsigned short* Mlo = Mhi + (size_t)K * O * E;         // [K][O][E] bf16 lo

    precompute_M<<<(K * O * E) / 256, 256, 0, stream>>>(Q, bil, Mhi, Mlo);
    fused_entmax<<<BATCH * K, 256, 0, stream>>>(x, Mhi, Mlo, values, out);
}

// Round 5
// 297.308 us; speedup vs baseline: 3.7965x; 1.5073x over previous
//
#include <hip/hip_runtime.h>
#include <hip/hip_bf16.h>

#define E 128
#define F 128
#define O 64
#define K 8
#define BATCH 2048
#define NEWTON_IT 9

typedef __attribute__((ext_vector_type(8))) short bf8;     // 8 bf16 (4 VGPR)
typedef __attribute__((ext_vector_type(16))) float f16x;   // MFMA 32x32 accumulator

// ---------------------------------------------------------------------------
// Kernel A: M[k,o,x] = 0.5 * sum_y bil[k,x,y] * Q[k,o,y], stored as truncated
// bf16 hi/lo planes in FRAGMENT-MAJOR layout: [k][(s*2+h)][o][8] where
// x = s*16 + h*8 + e.  Kernel B's A-loads are then lane-coalesced.
// ---------------------------------------------------------------------------
__global__ __launch_bounds__(256) void precompute_M(const float* __restrict__ Q,
                                                    const float* __restrict__ bil,
                                                    unsigned short* __restrict__ Mhi,
                                                    unsigned short* __restrict__ Mlo) {
    int idx = blockIdx.x * 256 + threadIdx.x;   // ((kk*O + o)*E + x)
    int x  = idx & 127;
    int o  = (idx >> 7) & 63;
    int kk = idx >> 13;
    const float4* br = (const float4*)(bil + (size_t)(kk * E + x) * E);
    const float4* qr = (const float4*)(Q + (size_t)(kk * O + o) * E);
    float acc = 0.f;
#pragma unroll 8
    for (int y = 0; y < E / 4; ++y) {
        float4 bv = br[y], qv = qr[y];
        acc = fmaf(bv.x, qv.x, acc);
        acc = fmaf(bv.y, qv.y, acc);
        acc = fmaf(bv.z, qv.z, acc);
        acc = fmaf(bv.w, qv.w, acc);
    }
    float m = 0.5f * acc;
    unsigned um = __float_as_uint(m);
    float hi = __uint_as_float(um & 0xFFFF0000u);
    float lo = m - hi;
    int s = x >> 4, h = (x >> 3) & 1, e = x & 7;
    int nidx = kk * (O * E) + (((s * 2 + h) * 64 + o) << 3) + e;
    Mhi[nidx] = (unsigned short)(um >> 16);
    Mlo[nidx] = (unsigned short)(__float_as_uint(lo) >> 16);
}

// split a,b into truncated-bf16 hi words + lo words, packed pairwise
#define SPLIT_PK(a, b, hw, lw)                                              \
    {                                                                       \
        unsigned ua = __float_as_uint(a), ub = __float_as_uint(b);          \
        float la = (a) - __uint_as_float(ua & 0xFFFF0000u);                 \
        float lb = (b) - __uint_as_float(ub & 0xFFFF0000u);                 \
        hw = (ua >> 16) | (ub & 0xFFFF0000u);                               \
        lw = (__float_as_uint(la) >> 16) | (__float_as_uint(lb) & 0xFFFF0000u); \
    }

// ---------------------------------------------------------------------------
// Kernel B: one block per b; x loaded+split ONCE into regs, then 8 heads:
// MFMA GEMM (3-product bf16 split) -> LDS transpose -> Newton entmax -> out.
// Wave w: f in [32w,32w+32). C: col = l&31 = f_local, row-decode = o_local.
// Newton: thread t owns row o=t>>2, quad-lane q=t&3; xor1/2 reductions only.
// ---------------------------------------------------------------------------
__global__ __launch_bounds__(256, 3) void fused_entmax(
        const float* __restrict__ xg,
        const unsigned short* __restrict__ Mhi,
        const unsigned short* __restrict__ Mlo,
        const float* __restrict__ values,
        float* __restrict__ out) {
    __shared__ float lds[O * 132];           // 33792 B

    int b = blockIdx.x;
    const float* xb = xg + (size_t)b * (F * E);

    int tid  = threadIdx.x;
    int w    = tid >> 6, l = tid & 63;
    int lo31 = l & 31;
    int hl   = l >> 5;                       // K-half: x-chunk 0 or 8
    int fcol = w * 32 + lo31;

    // ---- B operand once per block: x[fcol][s*16+hl*8 .. +8), split hi/lo ----
    bf8 Bh[8], Bl[8];
#pragma unroll
    for (int s = 0; s < 8; ++s) {
        const float* p = xb + (size_t)fcol * E + s * 16 + hl * 8;
        float4 v0 = *(const float4*)p;
        float4 v1 = *(const float4*)(p + 4);
        union { bf8 v; unsigned u[4]; } H, L;
        SPLIT_PK(v0.x, v0.y, H.u[0], L.u[0]);
        SPLIT_PK(v0.z, v0.w, H.u[1], L.u[1]);
        SPLIT_PK(v1.x, v1.y, H.u[2], L.u[2]);
        SPLIT_PK(v1.z, v1.w, H.u[3], L.u[3]);
        Bh[s] = H.v;
        Bl[s] = L.v;
    }

    int orow = tid >> 2;
    int q    = tid & 3;

#pragma unroll 1
    for (int kh = 0; kh < K; ++kh) {
        const unsigned short* mh = Mhi + (size_t)kh * (O * E);
        const unsigned short* ml = Mlo + (size_t)kh * (O * E);

        // ---- MFMA K-loop: acc = Ah*Bh + Ah*Bl + Al*Bh (coalesced A-loads) ----
        f16x acc0{}, acc1{};
#pragma unroll
        for (int s = 0; s < 8; ++s) {
            int base = ((s * 2 + hl) * 64) << 3;
            bf8 a0h = *(const bf8*)(mh + base + (lo31 << 3));
            bf8 a0l = *(const bf8*)(ml + base + (lo31 << 3));
            bf8 a1h = *(const bf8*)(mh + base + ((lo31 + 32) << 3));
            bf8 a1l = *(const bf8*)(ml + base + ((lo31 + 32) << 3));
            acc0 = __builtin_amdgcn_mfma_f32_32x32x16_bf16(a0l, Bh[s], acc0, 0, 0, 0);
            acc0 = __builtin_amdgcn_mfma_f32_32x32x16_bf16(a0h, Bl[s], acc0, 0, 0, 0);
            acc0 = __builtin_amdgcn_mfma_f32_32x32x16_bf16(a0h, Bh[s], acc0, 0, 0, 0);
            acc1 = __builtin_amdgcn_mfma_f32_32x32x16_bf16(a1l, Bh[s], acc1, 0, 0, 0);
            acc1 = __builtin_amdgcn_mfma_f32_32x32x16_bf16(a1h, Bl[s], acc1, 0, 0, 0);
            acc1 = __builtin_amdgcn_mfma_f32_32x32x16_bf16(a1h, Bh[s], acc1, 0, 0, 0);
        }

        // ---- transpose C into lds[o][f] (stride 132) ----
        if (kh) __syncthreads();             // prev head's reads done
#pragma unroll
        for (int r = 0; r < 16; ++r) {
            int ol = (r & 3) + ((r >> 2) << 3) + (hl << 2);
            lds[ol * 132 + fcol]        = acc0[r];
            lds[(ol + 32) * 132 + fcol] = acc1[r];
        }
        __syncthreads();

        // ---- Newton entmax on row orow (128 elems across 4-lane quad) ----
        float z[32];
#pragma unroll
        for (int j = 0; j < 8; ++j) {
            float4 v = *(const float4*)&lds[orow * 132 + q * 4 + 16 * j];
            z[4 * j + 0] = v.x;
            z[4 * j + 1] = v.y;
            z[4 * j + 2] = v.z;
            z[4 * j + 3] = v.w;
        }

        float m0 = z[0], m1 = z[1], m2 = z[2], m3 = z[3];
#pragma unroll
        for (int i = 4; i < 32; i += 4) {
            m0 = fmaxf(m0, z[i]);
            m1 = fmaxf(m1, z[i + 1]);
            m2 = fmaxf(m2, z[i + 2]);
            m3 = fmaxf(m3, z[i + 3]);
        }
        float mx = fmaxf(fmaxf(m0, m1), fmaxf(m2, m3));
        mx = fmaxf(mx, __shfl_xor(mx, 1));
        mx = fmaxf(mx, __shfl_xor(mx, 2));

        float t = mx - 1.0f;
#pragma unroll
        for (int it = 0; it < NEWTON_IT; ++it) {
            float s0 = 0.f, s1 = 0.f, s2 = 0.f, s3 = 0.f;
            float a0 = 0.f, a1 = 0.f;
#pragma unroll
            for (int i = 0; i < 32; i += 4) {
                float d0 = fmaxf(z[i] - t, 0.f);
                float d1 = fmaxf(z[i + 1] - t, 0.f);
                float d2 = fmaxf(z[i + 2] - t, 0.f);
                float d3 = fmaxf(z[i + 3] - t, 0.f);
                s0 = fmaf(d0, d0, s0);
                s1 = fmaf(d1, d1, s1);
                s2 = fmaf(d2, d2, s2);
                s3 = fmaf(d3, d3, s3);
                a0 += d0 + d1;
                a1 += d2 + d3;
            }
            float s  = (s0 + s1) + (s2 + s3);
            float sl = a0 + a1;
            s  += __shfl_xor(s, 1);
            s  += __shfl_xor(s, 2);
            sl += __shfl_xor(sl, 1);
            sl += __shfl_xor(sl, 2);
            t += (s - 1.0f) / (sl + sl);     // convex, from below: no overshoot
        }

        // ---- normalizer (recompute d, no array) ----
        float s0 = 0.f, s1 = 0.f, s2 = 0.f, s3 = 0.f;
#pragma unroll
        for (int i = 0; i < 32; i += 4) {
            float d0 = fmaxf(z[i] - t, 0.f);
            float d1 = fmaxf(z[i + 1] - t, 0.f);
            float d2 = fmaxf(z[i + 2] - t, 0.f);
            float d3 = fmaxf(z[i + 3] - t, 0.f);
            s0 = fmaf(d0, d0, s0);
            s1 = fmaf(d1, d1, s1);
            s2 = fmaf(d2, d2, s2);
            s3 = fmaf(d3, d3, s3);
        }
        float s = (s0 + s1) + (s2 + s3);
        s += __shfl_xor(s, 1);
        s += __shfl_xor(s, 2);
        float inv = 1.0f / s;

        // ---- scale by values, write out ----
        const float* vr = values + (size_t)(kh * O + orow) * F;
        float* op = out + (((size_t)b * K + kh) * O + orow) * (size_t)F;
#pragma unroll
        for (int j = 0; j < 8; ++j) {
            int fb = q * 4 + 16 * j;
            float4 vv = *(const float4*)(vr + fb);
            float d0 = fmaxf(z[4 * j + 0] - t, 0.f);
            float d1 = fmaxf(z[4 * j + 1] - t, 0.f);
            float d2 = fmaxf(z[4 * j + 2] - t, 0.f);
            float d3 = fmaxf(z[4 * j + 3] - t, 0.f);
            float4 ov;
            ov.x = d0 * d0 * inv * vv.x;
            ov.y = d1 * d1 * inv * vv.y;
            ov.z = d2 * d2 * inv * vv.z;
            ov.w = d3 * d3 * inv * vv.w;
            *(float4*)(op + fb) = ov;
        }
    }
}

extern "C" void kernel_launch(void* const* d_in, const int* in_sizes, int n_in,
                              void* d_out, int out_size, void* d_ws, size_t ws_size,
                              hipStream_t stream) {
    const float* x      = (const float*)d_in[0];   // [B, F, E]
    const float* Q      = (const float*)d_in[1];   // [K, O, E]
    const float* bil    = (const float*)d_in[2];   // [K, E, E]
    const float* values = (const float*)d_in[3];   // [K, O, F]
    float* out = (float*)d_out;                    // [B, K, O, F]

    unsigned short* Mhi = (unsigned short*)d_ws;           // [K][16][O][8] bf16 hi
    unsigned short* Mlo = Mhi + (size_t)K * O * E;         // same layout, lo

    precompute_M<<<(K * O * E) / 256, 256, 0, stream>>>(Q, bil, Mhi, Mlo);
    fused_entmax<<<BATCH, 256, 0, stream>>>(x, Mhi, Mlo, values, out);
}